// Round 5
// baseline (652.768 us; speedup 1.0000x reference)
//
#include <hip/hip_runtime.h>

typedef short short8 __attribute__((ext_vector_type(8)));
typedef float floatx4 __attribute__((ext_vector_type(4)));

#define ALPHA 50.0f
#define BN_EPS 1e-5f

// d_out regions (fp32 elements): vlad [0,262144), sa [262144,8650752), feature [8650752,25427968)
#define SA_BASE   262144L
#define FEAT_BASE 8650752L

// d_ws layout (bytes) — max used = 157,107,200 B (< 172,318,720 B proven-safe bound)
#define PART_OFF  0L           // part f32 [32][64][64][128] = 67,108,864 B — aliases dead T (written only after k_conv)
#define T_OFF     0L           // T: padded NHWC bf16 [32][130][130][128] = 138,444,800 B
#define WB_OFF    138444800L   // wB bf16 [9][128][128] = 294,912 B
#define WNA_OFF   138739712L   // wnA bf16 [64][128] = 16,384 B
#define AW_OFF    138756096L   // aw bf16 [32][64][4096] = 16,777,216 B
#define ASUMP_OFF 155533312L   // asumP f32 [32][64][64] = 524,288 B
#define VTMP_OFF  156057600L   // vtmp f32 [32][8192] = 1,048,576 B
#define GPART_OFF 157106176L   // gpart f32 [32][8] = 1,024 B

__device__ __forceinline__ unsigned short f2bf(float f) {
    unsigned u = __builtin_bit_cast(unsigned, f);
    u = u + 0x7FFFu + ((u >> 16) & 1u);
    return (unsigned short)(u >> 16);
}

__device__ __forceinline__ void gl_lds16(const void* g, void* l) {
    __builtin_amdgcn_global_load_lds(
        (const __attribute__((address_space(1))) unsigned int*)g,
        (__attribute__((address_space(3))) unsigned int*)l, 16, 0, 0);
}

// ---------------- prep: weight transforms ----------------
__global__ __launch_bounds__(256) void k_prep(const float* __restrict__ conv_w,
                                              const float* __restrict__ vlad_w,
                                              unsigned short* __restrict__ wB,
                                              unsigned short* __restrict__ wnA) {
    int b = blockIdx.x, t = threadIdx.x;
    if (b < 576) {
        int idx = b * 256 + t;                   // 0..147455
        int ci = idx & 127, co = (idx >> 7) & 127, tap = idx >> 14;
        float w = conv_w[(co * 128 + ci) * 9 + tap];
        wB[(tap * 128 + co) * 128 + ci] = f2bf(w);
    } else if (t < 64) {
        int k = t;
        float s = 0.0f;
        for (int c = 0; c < 128; c++) { float w = vlad_w[c * 64 + k]; s += w * w; }
        float rs = 1.0f / fmaxf(sqrtf(s), 1e-12f);
        for (int c = 0; c < 128; c++) wnA[k * 128 + c] = f2bf(vlad_w[c * 64 + k] * rs);
    }
}

// ---------------- zero-fill T borders (row iy=0, col ix=0) ----------------
__global__ __launch_bounds__(256) void k_border(unsigned short* __restrict__ T) {
    int n = blockIdx.x, t = threadIdx.x;
    uint4 z = make_uint4(0, 0, 0, 0);
    for (int i = t; i < 4128; i += 256) {
        long e;
        if (i < 2080) {                          // row 0: 130 ix * 16 octets
            int ix = i >> 4, oct = i & 15;
            e = (((long)n * 130 + 0) * 130 + ix) * 128 + oct * 8;
        } else {                                 // col 0, rows 1..128
            int j = i - 2080;
            int row = (j >> 4) + 1, oct = j & 15;
            e = (((long)n * 130 + row) * 130 + 0) * 128 + oct * 8;
        }
        *(uint4*)(T + e) = z;
    }
}

// ---------------- NCHW fp32 -> padded NHWC bf16 (full-line writes) ----------------
__global__ __launch_bounds__(256) void k_xform(const float* __restrict__ in,
                                               unsigned short* __restrict__ T) {
    int y = blockIdx.x, n = blockIdx.y, t = threadIdx.x;
    __shared__ float ls[64 * 133];
    for (int cc = 0; cc < 2; cc++) {
        __syncthreads();
        int ci0 = cc * 64;
#pragma unroll
        for (int i = 0; i < 8; i++) {
            int idx = i * 256 + t;               // 0..2047 float4s
            int ci = idx >> 5, xq = idx & 31;
            float4 v = *(const float4*)(in + ((((long)n * 128 + ci0 + ci) * 128 + y) * 128 + xq * 4));
            *(float4*)(&ls[ci * 133 + xq * 4]) = v;
        }
        __syncthreads();
#pragma unroll
        for (int i = 0; i < 4; i++) {
            int idx = i * 256 + t;
            int x = idx >> 3, oct = idx & 7;
            short8 pk;
#pragma unroll
            for (int j = 0; j < 8; j++)
                pk[j] = (short)f2bf(ls[(oct * 8 + j) * 133 + x]);
            long e = (((long)n * 130 + y + 1) * 130 + (x + 1)) * 128 + ci0 + oct * 8;
            *(short8*)(T + e) = pk;
        }
    }
}

// ---------------- conv3x3 s2 + BN + ReLU + L2norm + sa/softmax (pipelined staging) ----------------
// One output row (64 pix) per block. Double-buffered A-tiles bufA/bufB (static names for alias
// disambiguation). Per chunk: flat octets [r(3)][p(65)][o8'(8)], o8'=o8^(p&7), ix=2p+(o8>>2), oct=o8&3.
// Epilogue overlay: lsT [128 co][72 m] in bufA.
__global__ __launch_bounds__(256) void k_conv(const unsigned short* __restrict__ T,
                                              const unsigned short* __restrict__ wB,
                                              const float* __restrict__ gamma,
                                              const float* __restrict__ beta,
                                              const float* __restrict__ mean,
                                              const float* __restrict__ var,
                                              const unsigned short* __restrict__ wnA,
                                              const float* __restrict__ vlad_b,
                                              float* __restrict__ out,
                                              unsigned short* __restrict__ aw) {
    int y = blockIdx.x, n = blockIdx.y;
    int t = threadIdx.x, lane = t & 63, w = t >> 6;
    int wm = w >> 1, wn = w & 1;
    int s = lane & 15, q = lane >> 4;

    __shared__ __align__(16) short bufA[12480];  // 25KB chunk buffer 0 / epilogue lsT overlay
    __shared__ __align__(16) short bufB[12480];  // 25KB chunk buffer 1
    __shared__ float lsq[128];

    floatx4 acc[2][4];
#pragma unroll
    for (int a = 0; a < 2; a++)
#pragma unroll
        for (int b = 0; b < 4; b++) acc[a][b] = (floatx4){0.f, 0.f, 0.f, 0.f};

    const unsigned short* Tbase = T + (((long)n * 130 + 2 * y) * 130) * 128;
    int bbase0 = (wn * 64 + s) * 128 + q * 8;

    // stage chunk cc (32 ci) into dst: 1560 octets (3 rows x 520)
    auto STAGE = [&](short* dst, int cc) {
        const unsigned short* Tc = Tbase + cc * 32;
#pragma unroll
        for (int i = 0; i < 7; i++) {
            int f = i * 256 + t;
            short* lbase = dst + 2048 * i + 512 * w;   // wave-uniform
            if (f < 1560) {
                int r = f / 520;
                int rem = f - r * 520;
                int p = rem >> 3;
                int o8 = (rem & 7) ^ (p & 7);
                int ix = 2 * p + (o8 >> 2);
                int oct = o8 & 3;
                gl_lds16(Tc + (((long)(r * 130 + ix)) << 7) + (oct << 3), lbase);
            }
        }
    };
    auto COMPUTE = [&](const short* sb, int cc) {
        int ci0 = cc * 32;
#pragma unroll
        for (int tap = 0; tap < 9; tap++) {
            const int dy = tap / 3, dx = tap % 3;
            short8 af[2], bf[4];
#pragma unroll
            for (int tm = 0; tm < 2; tm++) {
                int x = wm * 32 + tm * 16 + s;
                int p = x + (dx >> 1);
                int o8p = (((dx & 1) << 2) | q) ^ (p & 7);
                af[tm] = *(const short8*)(&sb[(((dy * 65 + p) << 3) + o8p) << 3]);
            }
#pragma unroll
            for (int tn = 0; tn < 4; tn++)
                bf[tn] = *(const short8*)(wB + bbase0 + tap * 16384 + tn * 2048 + ci0);
#pragma unroll
            for (int tm = 0; tm < 2; tm++)
#pragma unroll
                for (int tn = 0; tn < 4; tn++)
                    acc[tm][tn] = __builtin_amdgcn_mfma_f32_16x16x32_bf16(af[tm], bf[tn], acc[tm][tn], 0, 0, 0);
        }
    };

    // software pipeline: stage(c+1) flies across the barrier (counted vmcnt, never 0 mid-loop)
    STAGE(bufA, 0);
    STAGE(bufB, 1);
    asm volatile("s_waitcnt vmcnt(6)\n\ts_barrier" ::: "memory");
    COMPUTE(bufA, 0);
    asm volatile("s_barrier" ::: "memory");
    STAGE(bufA, 2);
    asm volatile("s_waitcnt vmcnt(6)\n\ts_barrier" ::: "memory");
    COMPUTE(bufB, 1);
    asm volatile("s_barrier" ::: "memory");
    STAGE(bufB, 3);
    asm volatile("s_waitcnt vmcnt(6)\n\ts_barrier" ::: "memory");
    COMPUTE(bufA, 2);
    asm volatile("s_barrier" ::: "memory");
    asm volatile("s_waitcnt vmcnt(0)\n\ts_barrier" ::: "memory");
    COMPUTE(bufB, 3);

    // ---- BN + ReLU ----
    float inv[4], bt[4];
#pragma unroll
    for (int tn = 0; tn < 4; tn++) {
        int co = wn * 64 + tn * 16 + s;
        inv[tn] = gamma[co] / sqrtf(var[co] + BN_EPS);
        bt[tn] = beta[co] - mean[co] * inv[tn];
    }
#pragma unroll
    for (int tm = 0; tm < 2; tm++)
#pragma unroll
        for (int tn = 0; tn < 4; tn++)
#pragma unroll
            for (int r = 0; r < 4; r++) {
                float f = acc[tm][tn][r] * inv[tn] + bt[tn];
                acc[tm][tn][r] = fmaxf(f, 0.0f);
            }
    // ---- channel L2 norm ----
#pragma unroll
    for (int tm = 0; tm < 2; tm++)
#pragma unroll
        for (int r = 0; r < 4; r++) {
            float p = 0.f;
#pragma unroll
            for (int tn = 0; tn < 4; tn++) { float f = acc[tm][tn][r]; p += f * f; }
            p += __shfl_xor(p, 1); p += __shfl_xor(p, 2);
            p += __shfl_xor(p, 4); p += __shfl_xor(p, 8);
            if (s == 0) lsq[wn * 64 + wm * 32 + tm * 16 + q * 4 + r] = p;
        }
    __syncthreads();
    float scl[2][4];
#pragma unroll
    for (int tm = 0; tm < 2; tm++)
#pragma unroll
        for (int r = 0; r < 4; r++) {
            int m = wm * 32 + tm * 16 + q * 4 + r;
            float tot = lsq[m] + lsq[64 + m];
            scl[tm][r] = 1.0f / fmaxf(sqrtf(tot), 1e-12f);
        }
    short* lsT = bufA;                           // [128 co][72 m] overlay (9216 shorts <= 12480)
    long pixbase = (long)n * 4096 + y * 64;
#pragma unroll
    for (int tm = 0; tm < 2; tm++)
#pragma unroll
        for (int r = 0; r < 4; r++) {
            int m = wm * 32 + tm * 16 + q * 4 + r;
#pragma unroll
            for (int tn = 0; tn < 4; tn++) {
                int co = wn * 64 + tn * 16 + s;
                float xv = acc[tm][tn][r] * scl[tm][r];
                out[FEAT_BASE + (pixbase + m) * 128 + co] = xv;
                lsT[co * 72 + m] = (short)f2bf(xv);
            }
        }
    __syncthreads();

    // ---- soft-assign GEMM: logits[64 k][64 pix]; wave owns 16 pixels ----
    floatx4 acc2[4];
#pragma unroll
    for (int a = 0; a < 4; a++) acc2[a] = (floatx4){0.f, 0.f, 0.f, 0.f};
    int pixw = w * 16;
#pragma unroll
    for (int kk = 0; kk < 4; kk++) {
        int c0 = kk * 32 + q * 8;
        short8 af2[4], bf2;
#pragma unroll
        for (int tm = 0; tm < 4; tm++)
            af2[tm] = *(const short8*)(wnA + (tm * 16 + s) * 128 + c0);
#pragma unroll
        for (int j = 0; j < 8; j++)
            bf2[j] = lsT[(c0 + j) * 72 + pixw + s];
#pragma unroll
        for (int tm = 0; tm < 4; tm++)
            acc2[tm] = __builtin_amdgcn_mfma_f32_16x16x32_bf16(af2[tm], bf2, acc2[tm], 0, 0, 0);
    }
    long sabase = SA_BASE + (long)n * 262144 + y * 64 + pixw;
#pragma unroll
    for (int tm = 0; tm < 4; tm++)
#pragma unroll
        for (int r = 0; r < 4; r++) {
            int k = tm * 16 + q * 4 + r;
            out[sabase + (long)k * 4096 + s] = acc2[tm][r];
        }
    // softmax over k per pixel
    float bv2[4][4];
#pragma unroll
    for (int tm = 0; tm < 4; tm++)
#pragma unroll
        for (int r = 0; r < 4; r++) bv2[tm][r] = vlad_b[tm * 16 + q * 4 + r];
    float M = -1e30f;
#pragma unroll
    for (int tm = 0; tm < 4; tm++)
#pragma unroll
        for (int r = 0; r < 4; r++)
            M = fmaxf(M, ALPHA * (acc2[tm][r] + bv2[tm][r]));
    M = fmaxf(M, __shfl_xor(M, 16)); M = fmaxf(M, __shfl_xor(M, 32));
    float S = 0.f;
#pragma unroll
    for (int tm = 0; tm < 4; tm++)
#pragma unroll
        for (int r = 0; r < 4; r++) {
            float p = expf(ALPHA * (acc2[tm][r] + bv2[tm][r]) - M);
            acc2[tm][r] = p; S += p;
        }
    S += __shfl_xor(S, 16); S += __shfl_xor(S, 32);
    float rS = 1.0f / S;
    // a -> aw bf16 [n][k][4096] (16-lane 32B runs)
    long awbase = ((long)n * 64) * 4096 + y * 64 + pixw + s;
#pragma unroll
    for (int tm = 0; tm < 4; tm++)
#pragma unroll
        for (int r = 0; r < 4; r++) {
            int k = tm * 16 + q * 4 + r;
            aw[awbase + (long)k * 4096] = f2bf(acc2[tm][r] * rS);
        }
}

// ---------------- VLAD stage 1: per-row partial GEMM + asum (no atomics) ----------------
// Block (y,n): 64 pixels. Reads aw bf16 + feature f32 (transposed in LDS), writes part[n][y] slot.
__global__ __launch_bounds__(256) void k_vlad1(const unsigned short* __restrict__ aw,
                                               const float* __restrict__ feat,
                                               float* __restrict__ part,
                                               float* __restrict__ asumP) {
    int y = blockIdx.x, n = blockIdx.y;
    int t = threadIdx.x, lane = t & 63, w = t >> 6;
    int s = lane & 15, q = lane >> 4;

    __shared__ __align__(16) short lsX[128 * 72];  // xn^T bf16 [c][pix]
    __shared__ __align__(16) short lsAa[64 * 72];  // a bf16 [k][pix]

    // stage aw rows: thread t -> k = t>>2, seg = t&3 (16 pix each)
    {
        int k = t >> 2, seg = t & 3;
        const unsigned short* src = aw + ((long)n * 64 + k) * 4096 + y * 64 + seg * 16;
        short8 v0 = *(const short8*)(src);
        short8 v1 = *(const short8*)(src + 8);
        *(short8*)(&lsAa[k * 72 + seg * 16]) = v0;
        *(short8*)(&lsAa[k * 72 + seg * 16 + 8]) = v1;
    }
    // stage feature transposed: thread t -> pix = t>>2, cs = t&3 (32 c each)
    {
        int pix = t >> 2, cs = t & 3;
        const float* src = feat + FEAT_BASE + ((long)n * 4096 + y * 64 + pix) * 128 + cs * 32;
#pragma unroll
        for (int f4 = 0; f4 < 8; f4++) {
            float4 v = *(const float4*)(src + f4 * 4);
            int c = cs * 32 + f4 * 4;
            lsX[(c + 0) * 72 + pix] = (short)f2bf(v.x);
            lsX[(c + 1) * 72 + pix] = (short)f2bf(v.y);
            lsX[(c + 2) * 72 + pix] = (short)f2bf(v.z);
            lsX[(c + 3) * 72 + pix] = (short)f2bf(v.w);
        }
    }
    __syncthreads();
    // asum per k over this row's 64 pixels
    if (t < 64) {
        float sacc = 0.f;
#pragma unroll
        for (int p = 0; p < 64; p++) {
            unsigned short u = (unsigned short)lsAa[t * 72 + p];
            unsigned ui = ((unsigned)u) << 16;
            sacc += __builtin_bit_cast(float, ui);
        }
        asumP[((long)n * 64 + y) * 64 + t] = sacc;
    }
    // GEMM: part[64 k][128 c] = a(k,pix) . xn(c,pix); wave owns [32 k][64 c] quadrant
    floatx4 acc3[2][4];
#pragma unroll
    for (int a = 0; a < 2; a++)
#pragma unroll
        for (int b = 0; b < 4; b++) acc3[a][b] = (floatx4){0.f, 0.f, 0.f, 0.f};
    int kh = (w >> 1) * 32, ch0 = (w & 1) * 64;
#pragma unroll
    for (int pc = 0; pc < 2; pc++) {
        int p0 = pc * 32 + q * 8;
        short8 aA[2], bB[4];
#pragma unroll
        for (int tk = 0; tk < 2; tk++)
            aA[tk] = *(const short8*)(&lsAa[(kh + tk * 16 + s) * 72 + p0]);
#pragma unroll
        for (int tc = 0; tc < 4; tc++)
            bB[tc] = *(const short8*)(&lsX[(ch0 + tc * 16 + s) * 72 + p0]);
#pragma unroll
        for (int tk = 0; tk < 2; tk++)
#pragma unroll
            for (int tc = 0; tc < 4; tc++)
                acc3[tk][tc] = __builtin_amdgcn_mfma_f32_16x16x32_bf16(aA[tk], bB[tc], acc3[tk][tc], 0, 0, 0);
    }
    float* pp = part + ((long)n * 64 + y) * 8192;
#pragma unroll
    for (int tk = 0; tk < 2; tk++)
#pragma unroll
        for (int r = 0; r < 4; r++) {
            int k = kh + tk * 16 + q * 4 + r;
#pragma unroll
            for (int tc = 0; tc < 4; tc++)
                pp[k * 128 + ch0 + tc * 16 + s] = acc3[tk][tc][r];
        }
}

// ---------------- VLAD reduce: sum 64 slots + center-subtract + intra-norm ----------------
__global__ __launch_bounds__(256) void k_vred(const float* __restrict__ part,
                                              const float* __restrict__ vlad_w,
                                              const float* __restrict__ asumP,
                                              float* __restrict__ vtmp,
                                              float* __restrict__ gpart) {
    int sub = blockIdx.x, n = blockIdx.y;
    int t = threadIdx.x, lane = t & 63, w = t >> 6;
    __shared__ float asumT[64];
    __shared__ float asumL[8];
    __shared__ float lsq[16];
    __shared__ float gred[4];

    if (t < 64) {
        int kl = t & 7, i0 = t >> 3;
        int k = sub * 8 + kl;
        float sacc = 0.f;
#pragma unroll
        for (int i = 0; i < 8; i++) sacc += asumP[((long)n * 64 + i0 + i * 8) * 64 + k];
        asumT[t] = sacc;
    }
    __syncthreads();
    if (t < 8) {
        float sacc = 0.f;
#pragma unroll
        for (int g = 0; g < 8; g++) sacc += asumT[g * 8 + t];
        asumL[t] = sacc;
    }
    __syncthreads();

    int e0 = sub * 1024;
    float v[4];
    const float* pb = part + (long)n * 64 * 8192;
#pragma unroll
    for (int jj = 0; jj < 4; jj++) {
        int e = e0 + jj * 256 + t;
        float sacc = 0.f;
#pragma unroll 8
        for (int c8 = 0; c8 < 64; c8++) sacc += pb[c8 * 8192 + e];
        int k = e >> 7, c = e & 127;
        sacc -= asumL[k - sub * 8] * vlad_w[c * 64 + k];
        v[jj] = sacc;
        float p = sacc * sacc;
        p += __shfl_xor(p, 1); p += __shfl_xor(p, 2); p += __shfl_xor(p, 4);
        p += __shfl_xor(p, 8); p += __shfl_xor(p, 16); p += __shfl_xor(p, 32);
        if (lane == 0) lsq[jj * 4 + w] = p;
    }
    __syncthreads();
    float gp = 0.f;
#pragma unroll
    for (int jj = 0; jj < 4; jj++) {
        float tot = lsq[jj * 4 + (w & 2)] + lsq[jj * 4 + (w & 2) + 1];
        float sc = 1.0f / fmaxf(sqrtf(tot), 1e-12f);
        v[jj] *= sc;
        gp += v[jj] * v[jj];
        vtmp[(long)n * 8192 + e0 + jj * 256 + t] = v[jj];
    }
    gp += __shfl_xor(gp, 1); gp += __shfl_xor(gp, 2); gp += __shfl_xor(gp, 4);
    gp += __shfl_xor(gp, 8); gp += __shfl_xor(gp, 16); gp += __shfl_xor(gp, 32);
    if (lane == 0) gred[w] = gp;
    __syncthreads();
    if (t == 0) gpart[n * 8 + sub] = gred[0] + gred[1] + gred[2] + gred[3];
}

// ---------------- VLAD final: global L2 scale ----------------
__global__ __launch_bounds__(256) void k_vfin(const float* __restrict__ vtmp,
                                              const float* __restrict__ gpart,
                                              float* __restrict__ out) {
    int n = blockIdx.x, t = threadIdx.x;
    __shared__ float sc2s;
    if (t == 0) {
        float s = 0.f;
#pragma unroll
        for (int i = 0; i < 8; i++) s += gpart[n * 8 + i];
        sc2s = 1.0f / fmaxf(sqrtf(s), 1e-12f);
    }
    __syncthreads();
    float sc2 = sc2s;
    for (int i = t; i < 8192; i += 256)
        out[(long)n * 8192 + i] = vtmp[(long)n * 8192 + i] * sc2;
}

extern "C" void kernel_launch(void* const* d_in, const int* in_sizes, int n_in,
                              void* d_out, int out_size, void* d_ws, size_t ws_size,
                              hipStream_t stream) {
    const float* input  = (const float*)d_in[0];
    const float* conv_w = (const float*)d_in[1];
    const float* gamma  = (const float*)d_in[2];
    const float* beta   = (const float*)d_in[3];
    const float* mean   = (const float*)d_in[4];
    const float* var    = (const float*)d_in[5];
    const float* vlad_w = (const float*)d_in[6];
    const float* vlad_b = (const float*)d_in[7];
    float* out = (float*)d_out;
    char* ws = (char*)d_ws;

    unsigned short* T   = (unsigned short*)(ws + T_OFF);
    float* part         = (float*)(ws + PART_OFF);   // aliases dead T
    unsigned short* wB  = (unsigned short*)(ws + WB_OFF);
    unsigned short* wnA = (unsigned short*)(ws + WNA_OFF);
    unsigned short* aw  = (unsigned short*)(ws + AW_OFF);
    float* asumP        = (float*)(ws + ASUMP_OFF);
    float* vtmp         = (float*)(ws + VTMP_OFF);
    float* gpart        = (float*)(ws + GPART_OFF);

    k_prep<<<577, 256, 0, stream>>>(conv_w, vlad_w, wB, wnA);
    k_border<<<32, 256, 0, stream>>>(T);
    k_xform<<<dim3(128, 32), 256, 0, stream>>>(input, T);
    k_conv<<<dim3(64, 32), 256, 0, stream>>>(T, wB, gamma, beta, mean, var, wnA, vlad_b, out, aw);
    k_vlad1<<<dim3(64, 32), 256, 0, stream>>>(aw, out, part, asumP);
    k_vred<<<dim3(8, 32), 256, 0, stream>>>(part, vlad_w, asumP, vtmp, gpart);
    k_vfin<<<32, 256, 0, stream>>>(vtmp, gpart, out);
}